// Round 1
// baseline (103.604 us; speedup 1.0000x reference)
//
#include <hip/hip_runtime.h>

// ApproxSiLU16 fixed-point: IN_FRAC=11, OUT_FRAC=10.
// seg LUT is exactly uniform: seg[i] = -16384 + i*1792 for i in [0,16].
// (linspace(-8,6,17)*2048 -> step 0.875*2048 = 1792, all integers exact)
#define MIN_SEG  (-16384)
#define MAX_SEG  (12288)
#define D_SEG    (1792)

__global__ __launch_bounds__(256)
void approx_silu_fxp_kernel(const float* __restrict__ x,
                            const int* __restrict__ silu_vals,
                            float* __restrict__ out,
                            int n4) {
    __shared__ int lut[17];
    if (threadIdx.x < 17) lut[threadIdx.x] = silu_vals[threadIdx.x];
    __syncthreads();

    const float4* __restrict__ x4 = reinterpret_cast<const float4*>(x);
    float4* __restrict__ o4 = reinterpret_cast<float4*>(out);

    int stride = gridDim.x * blockDim.x;
    for (int i = blockIdx.x * blockDim.x + threadIdx.x; i < n4; i += stride) {
        float4 v = x4[i];
        float r[4] = {v.x, v.y, v.z, v.w};
        float o[4];
        #pragma unroll
        for (int j = 0; j < 4; ++j) {
            // round-half-even matches jnp.round
            int xi = __float2int_rn(r[j] * 2048.0f);
            int out_int;
            if (xi > MAX_SEG) {
                // IN_FRAC - OUT_FRAC = 1 ; xi > 0 here so >> is fine
                out_int = xi >> 1;
            } else {
                int xc = max(xi, MIN_SEG);            // upper clamp implied by branch
                unsigned u = (unsigned)(xc - MIN_SEG); // 0 .. 16*1792
                int idx = min((int)(u / D_SEG), 15);   // searchsorted-left -1, see note
                int dx  = (int)u - idx * D_SEG;        // 0 .. 1792
                int y0 = lut[idx];
                int y1 = lut[idx + 1];
                // t_fx = ((dx << 10) + 896) / 1792, dx >= 0 so C div == floor div
                int t_fx = (dx * 1024 + 896) / D_SEG;
                // arithmetic >> matches Python floor shift for negative values
                out_int = y0 + ((t_fx * (y1 - y0) + 512) >> 10);
            }
            o[j] = (float)out_int * (1.0f / 1024.0f);
        }
        float4 ov = make_float4(o[0], o[1], o[2], o[3]);
        o4[i] = ov;
    }
}

extern "C" void kernel_launch(void* const* d_in, const int* in_sizes, int n_in,
                              void* d_out, int out_size, void* d_ws, size_t ws_size,
                              hipStream_t stream) {
    const float* x = (const float*)d_in[0];
    // d_in[1] = seg (unused: uniform, hard-derived), d_in[2] = silu_vals
    const int* silu_vals = (const int*)d_in[2];
    float* out = (float*)d_out;

    int n = in_sizes[0];            // 67,108,864
    int n4 = n >> 2;                // float4 elements (n is a multiple of 4)

    int block = 256;
    int grid = (n4 + block - 1) / block;
    if (grid > 2048) grid = 2048;   // grid-stride; ~8 blocks/CU across 256 CUs

    approx_silu_fxp_kernel<<<grid, block, 0, stream>>>(x, silu_vals, out, n4);
}